// Round 1
// baseline (259.056 us; speedup 1.0000x reference)
//
#include <hip/hip_runtime.h>

// RoiAlign / crop_and_resize: B=8, H=64, W=64, C=256, N=512, POOL=7
//
// R5: process boxes in y-sorted order. Theory: kernel (~122us) is
// HBM-fetch-bound (~10.7 B/cy/CU == per-CU HBM share) because concurrently
// live blocks read random y-rows -> full 4MiB image hot per XCD == L2 size
// -> thrash. Prologue kernel bitonic-sorts each image's 512 boxes by y1
// into a permutation (d_ws); main kernel indirects box reads AND output
// writes through it. Live working set becomes a ~25-row y-band (~1.7MiB),
// L2-resident. Output is bit-identical (same math per box, different order).
// Keep from R4: wave-per-output-row, 28 hoisted 16B/lane loads, %8
// image->XCD swizzle, nontemporal 1KB stores.

#define POOL  7
#define B_    8
#define H_    64
#define W_    64
#define C_    256
#define N_    512
#define CW    (C_ / 4)                  // 64 16B-vectors per spatial pixel
#define ROWS_PER_IMG (N_ * POOL)        // 3584 rows per image
#define ROWS_PER_BLOCK 4                // 4 waves per 256-thread block

typedef float v4f __attribute__((ext_vector_type(4)));

// ---- prologue: per-image bitonic sort of 512 boxes by y1 ----------------
__global__ __launch_bounds__(512) void sort_boxes_kernel(
    const float* __restrict__ boxes,   // [B,N,4] x1,y1,x2,y2
    int* __restrict__ perm)            // [B,N]
{
    const int b = blockIdx.x;          // 0..7
    const int t = threadIdx.x;         // 0..511
    __shared__ float key[N_];
    __shared__ int   idx[N_];
    key[t] = boxes[((b << 9) + t) * 4 + 1];   // y1
    idx[t] = t;
    __syncthreads();
    for (int k = 2; k <= N_; k <<= 1) {
        for (int j = k >> 1; j > 0; j >>= 1) {
            const int ixj = t ^ j;
            if (ixj > t) {
                const bool up = ((t & k) == 0);
                const float a = key[t], c = key[ixj];
                if (up ? (a > c) : (a < c)) {
                    key[t] = c; key[ixj] = a;
                    const int tmp = idx[t]; idx[t] = idx[ixj]; idx[ixj] = tmp;
                }
            }
            __syncthreads();
        }
    }
    perm[(b << 9) + t] = idx[t];
}

// ---- main kernel --------------------------------------------------------
__global__ __launch_bounds__(256) void roialign_kernel(
    const float* __restrict__ fm,      // [B,H,W,C]
    const float* __restrict__ boxes,   // [B,N,4] = x1,y1,x2,y2 normalized
    const int*  __restrict__ perm,     // [B,N] y-sorted box order
    float* __restrict__ out)           // [B,N,POOL,POOL,C]
{
    // XCD swizzle: image b sticks to XCD b (round-robin block dispatch).
    const int b    = blockIdx.x & 7;
    const int rblk = blockIdx.x >> 3;           // 0..895
    const int wave = threadIdx.x >> 6;          // 0..3
    const int lane = threadIdx.x & 63;
    const int row  = rblk * ROWS_PER_BLOCK + wave;   // 0..3583 (exact)
    const int ns   = row / POOL;                // sorted position 0..511
    const int py   = row - ns * POOL;           // 0..6

    // Indirect: actual box index (uniform per wave).
    const int n = __builtin_amdgcn_readfirstlane(perm[(b << 9) + ns]);

    const float* box = boxes + ((b << 9) + n) * 4;
    const float bx1 = box[0], by1 = box[1], bx2 = box[2], by2 = box[3];

    // Match reference expression order exactly:
    //   ys = y1*(H-1) + i * ((y2-y1)*(H-1)/(POOL-1))
    const float sy  = (by2 - by1) * 63.0f / 6.0f;
    const float sx  = (bx2 - bx1) * 63.0f / 6.0f;
    const float yv  = by1 * 63.0f + (float)py * sy;
    const float x0v = bx1 * 63.0f;

    const float yf = floorf(yv);
    const float fy = yv - yf;
    const int   y0 = (int)yf;
    const int   yt = min(max(y0,     0), H_ - 1);
    const int   yb = min(max(y0 + 1, 0), H_ - 1);
    const bool  vy = (yv >= 0.0f) && (yv <= 63.0f);

    const v4f* f4  = (const v4f*)fm;
    const int rowT = (b * (H_ * W_) + yt * W_) * CW + lane;
    const int rowB = (b * (H_ * W_) + yb * W_) * CW + lane;

    v4f* o4 = (v4f*)out + ((((b << 9) + n) * POOL + py) * POOL) * CW + lane;

    #pragma unroll
    for (int px = 0; px < POOL; ++px) {
        const float xv = x0v + (float)px * sx;
        const float xf = floorf(xv);
        const float fx = xv - xf;
        const int   x0 = (int)xf;
        const int   xl = min(max(x0,     0), W_ - 1);
        const int   xr = min(max(x0 + 1, 0), W_ - 1);
        const bool  valid = vy && (xv >= 0.0f) && (xv <= 63.0f);

        const v4f tl = f4[rowT + xl * CW];
        const v4f tr = f4[rowT + xr * CW];
        const v4f bl = f4[rowB + xl * CW];
        const v4f br = f4[rowB + xr * CW];

        const v4f top = tl + (tr - tl) * fx;
        const v4f bot = bl + (br - bl) * fx;
        v4f o = top + (bot - top) * fy;
        if (!valid) o = (v4f)(0.0f);

        __builtin_nontemporal_store(o, o4 + px * CW);
    }
}

extern "C" void kernel_launch(void* const* d_in, const int* in_sizes, int n_in,
                              void* d_out, int out_size, void* d_ws, size_t ws_size,
                              hipStream_t stream) {
    const float* fm    = (const float*)d_in[0];   // [8,64,64,256] fp32
    const float* boxes = (const float*)d_in[1];   // [8,512,4] fp32
    float* out         = (float*)d_out;           // [8,512,7,7,256] fp32
    int*   perm        = (int*)d_ws;              // [8,512] = 16 KB

    sort_boxes_kernel<<<B_, N_, 0, stream>>>(boxes, perm);

    // 4 row-waves per block; 896 blocks per image x 8 images = 7168 blocks.
    const int blocks = (ROWS_PER_IMG / ROWS_PER_BLOCK) * B_;
    roialign_kernel<<<blocks, 256, 0, stream>>>(fm, boxes, perm, out);
}

// Round 2
// 254.164 us; speedup vs baseline: 1.0192x; 1.0192x over previous
//
#include <hip/hip_runtime.h>

// RoiAlign / crop_and_resize: B=8, H=64, W=64, C=256, N=512, POOL=7
//
// R6: channel-sliced L2 residency. R5 post-mortem: y-sorting boxes was
// neutral — boxes avg 21 rows tall, so the live working set stays ~full
// image no matter the box order. Fix: slice C=256 into 2x128-ch passes,
// slice-major grid order. Concurrent blocks on an XCD then touch only a
// 2 MiB channel-slice of their image -> L2-resident (NT stores bypass L2,
// no pollution) -> gather reads become L2 hits. Fetch ~600MB -> ~34MB;
// floor = (34 fetch + 205 write)/6.6TB/s ~= 36us.
// Wave structure: one wave = (box-pair, py). Lanes 0-31 = box 2np
// (32 channel-quads of the 128-ch slice), lanes 32-63 = box 2np+1.
// Full lane utilization, stores = 2x512B contiguous segments.
// Keep: %8 image->XCD swizzle, 28 independent 16B/lane loads in flight,
// nontemporal stores. Sort prologue dropped.

#define POOL  7
#define B_    8
#define H_    64
#define W_    64
#define C_    256
#define N_    512
#define CW    (C_ / 4)                   // 64 16B-quads per spatial pixel
#define SLICES 2
#define QSL   (CW / SLICES)              // 32 quads per channel-slice
#define PAIRS (N_ / 2)                   // 256 box-pairs per image
#define ROWS_PER_IS (PAIRS * POOL)       // 1792 pair-rows per image-slice
#define ROWS_PER_BLOCK 4                 // 4 waves per 256-thread block
#define BLOCKS_PER_IS (ROWS_PER_IS / ROWS_PER_BLOCK)   // 448

typedef float v4f __attribute__((ext_vector_type(4)));

__global__ __launch_bounds__(256) void roialign_kernel(
    const float* __restrict__ fm,      // [B,H,W,C]
    const float* __restrict__ boxes,   // [B,N,4] = x1,y1,x2,y2 normalized
    float* __restrict__ out)           // [B,N,POOL,POOL,C]
{
    // XCD swizzle: image b sticks to XCD b (round-robin block dispatch).
    // Slice-major above that: all of slice 0 dispatches before slice 1,
    // so concurrently-live blocks on an XCD share one 2 MiB slice.
    const int b     = blockIdx.x & 7;
    const int t     = blockIdx.x >> 3;          // 0..895
    const int slice = (t >= BLOCKS_PER_IS) ? 1 : 0;
    const int rblk  = t - slice * BLOCKS_PER_IS;     // 0..447
    const int wave  = threadIdx.x >> 6;         // 0..3
    const int lane  = threadIdx.x & 63;
    const int rowp  = rblk * ROWS_PER_BLOCK + wave;  // 0..1791 (exact)
    const int np    = rowp / POOL;              // box-pair 0..255
    const int py    = rowp - np * POOL;         // 0..6

    const int h = lane >> 5;                    // which box of the pair
    const int q = lane & 31;                    // channel-quad within slice
    const int n = np * 2 + h;                   // box index 0..511
    const int qc = slice * QSL + q;             // channel-quad within C

    // Per-lane box params (lanes 0-31 broadcast one box, 32-63 the other).
    const v4f bx = ((const v4f*)boxes)[(b << 9) + n];
    const float bx1 = bx[0], by1 = bx[1], bx2 = bx[2], by2 = bx[3];

    // Match reference expression order exactly:
    //   ys = y1*(H-1) + i * ((y2-y1)*(H-1)/(POOL-1))
    const float sy  = (by2 - by1) * 63.0f / 6.0f;
    const float sx  = (bx2 - bx1) * 63.0f / 6.0f;
    const float yv  = by1 * 63.0f + (float)py * sy;
    const float x0v = bx1 * 63.0f;

    const float yf = floorf(yv);
    const float fy = yv - yf;
    const int   y0 = (int)yf;
    const int   yt = min(max(y0,     0), H_ - 1);
    const int   yb = min(max(y0 + 1, 0), H_ - 1);
    const bool  vy = (yv >= 0.0f) && (yv <= 63.0f);

    const v4f* f4  = (const v4f*)fm;
    const int rowT = (b * (H_ * W_) + yt * W_) * CW + qc;
    const int rowB = (b * (H_ * W_) + yb * W_) * CW + qc;

    v4f* o4 = (v4f*)out + ((((b << 9) + n) * POOL + py) * POOL) * CW + qc;

    #pragma unroll
    for (int px = 0; px < POOL; ++px) {
        const float xv = x0v + (float)px * sx;
        const float xf = floorf(xv);
        const float fx = xv - xf;
        const int   x0 = (int)xf;
        const int   xl = min(max(x0,     0), W_ - 1);
        const int   xr = min(max(x0 + 1, 0), W_ - 1);
        const bool  valid = vy && (xv >= 0.0f) && (xv <= 63.0f);

        const v4f tl = f4[rowT + xl * CW];
        const v4f tr = f4[rowT + xr * CW];
        const v4f bl = f4[rowB + xl * CW];
        const v4f br = f4[rowB + xr * CW];

        const v4f top = tl + (tr - tl) * fx;
        const v4f bot = bl + (br - bl) * fx;
        v4f o = top + (bot - top) * fy;
        if (!valid) o = (v4f)(0.0f);

        __builtin_nontemporal_store(o, o4 + px * CW);
    }
}

extern "C" void kernel_launch(void* const* d_in, const int* in_sizes, int n_in,
                              void* d_out, int out_size, void* d_ws, size_t ws_size,
                              hipStream_t stream) {
    const float* fm    = (const float*)d_in[0];   // [8,64,64,256] fp32
    const float* boxes = (const float*)d_in[1];   // [8,512,4] fp32
    float* out         = (float*)d_out;           // [8,512,7,7,256] fp32

    // 448 blocks per image-slice x 8 images x 2 slices = 7168 blocks.
    const int blocks = BLOCKS_PER_IS * SLICES * B_;
    roialign_kernel<<<blocks, 256, 0, stream>>>(fm, boxes, out);
}